// Round 9
// baseline (121.114 us; speedup 1.0000x reference)
//
#include <hip/hip_runtime.h>

#define NQ 12
#define NT 256   // 4 waves per block; one batch element per block; 16 amps/thread

typedef float v2 __attribute__((ext_vector_type(2)));

// ---------- GF(2)-linear index machinery (HW-verified R4/R6/R7/R8) ----------
__host__ __device__ constexpr int par12(int v) {
    v ^= v >> 8; v ^= v >> 4; v ^= v >> 2; v ^= v >> 1; return v & 1;
}
// ringInv (verified): x_k = y_k^y_{k+1} (k<=9); x10 = y11^y0^y10; x11 = y0^y11.
// LDS slot swizzle (verified conflict-free for all era patterns in R8).
__host__ __device__ constexpr int SL(int i) { return i ^ ((i >> 5) & 31); }

__device__ __forceinline__ v2 cmadd(v2 c, v2 a, v2 acc) {
    acc += c.x * a;
    v2 j; j.x = -a.y; j.y = a.x;
    acc += c.y * j;
    return acc;
}
__device__ __forceinline__ v2 cmul(v2 c, v2 a) { return cmadd(c, a, (v2){0.f, 0.f}); }
__device__ __forceinline__ void gate2(v2& A0, v2& A1, v2 u00, v2 u01, v2 u10, v2 u11) {
    v2 n0 = cmadd(u01, A1, cmul(u00, A0));
    v2 n1 = cmadd(u11, A1, cmul(u10, A0));
    A0 = n0; A1 = n1;
}
__device__ __forceinline__ v2 sel2(v2 a, v2 b, int c) { return c ? b : a; }

template <int ITERS>
__global__ __launch_bounds__(NT, 4) void qsim_kernel(
    const float* __restrict__ x,   // (B, 12) fp32
    const float* __restrict__ w,   // (2, 12, 3) fp32
    float* __restrict__ out)       // (B, 12) fp32
{
    __shared__ v2 sc[4096];                       // 32 KB state scratch
    __shared__ __align__(16) float fm[2][NQ][8];  // fused U = Rot*RY
    __shared__ float red[4][NQ];

    const int t  = threadIdx.x;
    const int L  = t & 63;
    const int Wv = t >> 6;        // wave id 0..3
    const int b  = blockIdx.x;

    // ---- fused gate matrices U = Rot(phi,theta,omega) * RY(x_q) ----
    if (t < 2 * NQ) {
        int l = t / NQ, q = t % NQ;
        float hy = 0.5f * x[b * NQ + q];
        float cy = cosf(hy), sy = sinf(hy);
        const float* wp = w + (l * NQ + q) * 3;
        float phi = wp[0], the = wp[1], om = wp[2];
        float c = cosf(0.5f * the), s = sinf(0.5f * the);
        float al = 0.5f * (phi + om), be = 0.5f * (phi - om);
        float ca = cosf(al), sa = sinf(al), cb = cosf(be), sb = sinf(be);
        float r00r =  ca * c, r00i = -sa * c;
        float r01r = -cb * s, r01i = -sb * s;
        float r10r =  cb * s, r10i = -sb * s;
        float r11r =  ca * c, r11i =  sa * c;
        float* m = fm[l][q];
        m[0] =  r00r * cy + r01r * sy;  m[1] =  r00i * cy + r01i * sy;  // U00
        m[2] = -r00r * sy + r01r * cy;  m[3] = -r00i * sy + r01i * cy;  // U01
        m[4] =  r10r * cy + r11r * sy;  m[5] =  r10i * cy + r11i * sy;  // U10
        m[6] = -r10r * sy + r11r * cy;  m[7] = -r10i * sy + r11i * cy;  // U11
    }

    // ---- era bases (R8-verified patterns) ----
    const int g0    = (Wv << 10) | (L << 4);
    const int rbase = SL(g0);                              // Q0 slot base
    const int q1i   = (Wv << 10) | ((L >> 4) << 8) | (L & 15);
    const int q1b   = SL(q1i);
    const int q2t   = (Wv << 6) | L;
    const int q2b   = q2t ^ ((q2t >> 5) & 31);
    const int L0 = L & 1, Wv0 = Wv & 1, Wv1 = Wv >> 1;
    // epilogue sign-flip masks per lane bit
    unsigned sm0 = (L & 1)  ? 0x80000000u : 0u;
    unsigned sm1 = (L & 2)  ? 0x80000000u : 0u;
    unsigned sm2 = (L & 4)  ? 0x80000000u : 0u;
    unsigned sm3 = (L & 8)  ? 0x80000000u : 0u;
    unsigned sm4 = (L & 16) ? 0x80000000u : 0u;
    unsigned sm5 = (L & 32) ? 0x80000000u : 0u;

    __syncthreads();   // fm ready  [barrier 1]

    for (int it = 0; it < ITERS; ++it) {
        // ==== post-ring1 state built DIRECTLY in registers ====
        // amp(i) = prod_q v_q[x_{11-q}], x = ringInv(i), i = (Wv<<10)|(L<<4)|r.
        // Wire selectors: s11=r0^r1 s10=r1^r2 s9=r2^r3 s8=r3^L0 s7..s3=L digrams
        // s2=L5^Wv0 s1=Wv0^Wv1^r0 s0=Wv1^r0. v_q[bit]=U|0> component = m[0..1]/m[4..5].
        v2 A[16];
        {
            // lane-constant product C over wires 7..2
            v2 C = sel2(*(const v2*)&fm[0][7][0], *(const v2*)&fm[0][7][4], (L ^ (L >> 1)) & 1);
            C = cmul(sel2(*(const v2*)&fm[0][6][0], *(const v2*)&fm[0][6][4], ((L >> 1) ^ (L >> 2)) & 1), C);
            C = cmul(sel2(*(const v2*)&fm[0][5][0], *(const v2*)&fm[0][5][4], ((L >> 2) ^ (L >> 3)) & 1), C);
            C = cmul(sel2(*(const v2*)&fm[0][4][0], *(const v2*)&fm[0][4][4], ((L >> 3) ^ (L >> 4)) & 1), C);
            C = cmul(sel2(*(const v2*)&fm[0][3][0], *(const v2*)&fm[0][3][4], ((L >> 4) ^ (L >> 5)) & 1), C);
            C = cmul(sel2(*(const v2*)&fm[0][2][0], *(const v2*)&fm[0][2][4], ((L >> 5) ^ Wv0) & 1), C);
            // E_{r0} = v1[Wv0^Wv1^r0] * v0[Wv1^r0]
            v2 v1a = sel2(*(const v2*)&fm[0][1][0], *(const v2*)&fm[0][1][4], Wv0 ^ Wv1);
            v2 v1b = sel2(*(const v2*)&fm[0][1][0], *(const v2*)&fm[0][1][4], Wv0 ^ Wv1 ^ 1);
            v2 v0a = sel2(*(const v2*)&fm[0][0][0], *(const v2*)&fm[0][0][4], Wv1);
            v2 v0b = sel2(*(const v2*)&fm[0][0][0], *(const v2*)&fm[0][0][4], Wv1 ^ 1);
            v2 A2[2];
            A2[0] = cmul(C, cmul(v1a, v0a));
            A2[1] = cmul(C, cmul(v1b, v0b));
            // x v11[r0^r1]
            v2 e0 = *(const v2*)&fm[0][11][0], e1 = *(const v2*)&fm[0][11][4];
            v2 A4[4];
            A4[0] = cmul(e0, A2[0]); A4[1] = cmul(e1, A2[1]);   // r1=0: sel=r0
            A4[2] = cmul(e1, A2[0]); A4[3] = cmul(e0, A2[1]);   // r1=1: sel=r0^1
            // x v10[r1^r2]
            v2 f0 = *(const v2*)&fm[0][10][0], f1 = *(const v2*)&fm[0][10][4];
            v2 A8[8];
#pragma unroll
            for (int rr = 0; rr < 8; ++rr) {
                int r1 = (rr >> 1) & 1, r2 = (rr >> 2) & 1;
                A8[rr] = cmul((r1 ^ r2) ? f1 : f0, A4[rr & 3]);
            }
            // H[r2,r3] = v9[r2^r3] * v8[r3^L0]
            v2 n0 = *(const v2*)&fm[0][9][0], n1 = *(const v2*)&fm[0][9][4];
            v2 m8a = sel2(*(const v2*)&fm[0][8][0], *(const v2*)&fm[0][8][4], L0);      // r3=0
            v2 m8b = sel2(*(const v2*)&fm[0][8][0], *(const v2*)&fm[0][8][4], L0 ^ 1);  // r3=1
            v2 H[4];
            H[0] = cmul(n0, m8a);  // r2=0,r3=0
            H[1] = cmul(n1, m8a);  // r2=1,r3=0
            H[2] = cmul(n1, m8b);  // r2=0,r3=1
            H[3] = cmul(n0, m8b);  // r2=1,r3=1
#pragma unroll
            for (int r = 0; r < 16; ++r)
                A[r] = cmul(H[((r >> 2) & 1) + 2 * (r >> 3)], A8[r & 7]);
        }

        // ==== gates wires 11..8 (Q0 reg bit j <-> wire 11-j) ====
#pragma unroll
        for (int j = 0; j < 4; ++j) {
            const int q = 11 - j;
            float4 lo = *(const float4*)&fm[1][q][0], hi = *(const float4*)&fm[1][q][4];
            v2 u00 = {lo.x, lo.y}, u01 = {lo.z, lo.w}, u10 = {hi.x, hi.y}, u11 = {hi.z, hi.w};
#pragma unroll
            for (int r0 = 0; r0 < 16; ++r0) {
                if (r0 & (1 << j)) continue;
                gate2(A[r0], A[r0 | (1 << j)], u00, u01, u10, u11);
            }
        }

        // ==== T1: Q0 -> Q1 (same-wave slot reuse: DS in-order, no barrier) ====
#pragma unroll
        for (int r = 0; r < 16; ++r) sc[rbase ^ r] = A[r];
#pragma unroll
        for (int r = 0; r < 16; ++r) A[r] = sc[q1b ^ ((r << 4) ^ (r >> 1))];

        // ==== gates wires 7..4 (Q1 reg bit j <-> wire 7-j) ====
#pragma unroll
        for (int j = 0; j < 4; ++j) {
            const int q = 7 - j;
            float4 lo = *(const float4*)&fm[1][q][0], hi = *(const float4*)&fm[1][q][4];
            v2 u00 = {lo.x, lo.y}, u01 = {lo.z, lo.w}, u10 = {hi.x, hi.y}, u11 = {hi.z, hi.w};
#pragma unroll
            for (int r0 = 0; r0 < 16; ++r0) {
                if (r0 & (1 << j)) continue;
                gate2(A[r0], A[r0 | (1 << j)], u00, u01, u10, u11);
            }
        }

        // ==== T2: Q1 -> Q2 (cross-wave) ====
#pragma unroll
        for (int r = 0; r < 16; ++r) sc[q1b ^ ((r << 4) ^ (r >> 1))] = A[r];
        __syncthreads();   // [barrier 2]
#pragma unroll
        for (int r = 0; r < 16; ++r) A[r] = sc[q2b ^ ((r << 8) ^ ((r & 3) << 3))];

        // ==== gates wires 3..0 (Q2 reg bit j <-> wire 3-j) ====
#pragma unroll
        for (int j = 0; j < 4; ++j) {
            const int q = 3 - j;
            float4 lo = *(const float4*)&fm[1][q][0], hi = *(const float4*)&fm[1][q][4];
            v2 u00 = {lo.x, lo.y}, u01 = {lo.z, lo.w}, u10 = {hi.x, hi.y}, u11 = {hi.z, hi.w};
#pragma unroll
            for (int r0 = 0; r0 < 16; ++r0) {
                if (r0 & (1 << j)) continue;
                gate2(A[r0], A[r0 | (1 << j)], u00, u01, u10, u11);
            }
        }

        // ==== epilogue: ring2 folded into signs (R8-verified masks) ====
        float A7 = 0.f, AC = 0.f, AE = 0.f, AFv = 0.f;
#pragma unroll
        for (int r = 0; r < 16; ++r) {
            float p = A[r].x * A[r].x + A[r].y * A[r].y;
            A7  += par12(r & 0x7) ? -p : p;
            AC  += par12(r & 0xC) ? -p : p;
            AE  += par12(r & 0xE) ? -p : p;
            AFv += par12(r & 0xF) ? -p : p;
        }
        // shared-prefix Walsh butterflies over lane bits 5..0
#define SSTG(X, SM, OFF) { float y_ = __uint_as_float(__float_as_uint(X) ^ (SM)); X = y_ + __shfl_xor(y_, OFF, 64); }
#define PSTG(X, OFF)     { X += __shfl_xor(X, OFF, 64); }
        float F = AFv, P = AFv;
        SSTG(F, sm5, 32); PSTG(P, 32); float C20 = F;
        SSTG(F, sm4, 16); PSTG(P, 16); PSTG(C20, 16); float C30 = F;
        SSTG(F, sm3, 8);  PSTG(P, 8);  PSTG(C20, 8);  PSTG(C30, 8);  float C38 = F;
        SSTG(F, sm2, 4);  PSTG(P, 4);  PSTG(C20, 4);  PSTG(C30, 4);  PSTG(C38, 4); float C3C = F;
        SSTG(F, sm1, 2);  PSTG(P, 2);  PSTG(C20, 2);  PSTG(C30, 2);  PSTG(C38, 2); PSTG(C3C, 2); float C3E = F;
        SSTG(F, sm0, 1);  PSTG(P, 1);  PSTG(C20, 1);  PSTG(C30, 1);  PSTG(C38, 1); PSTG(C3C, 1); PSTG(C3E, 1);
        float S7 = A7;
        SSTG(S7, sm5, 32); SSTG(S7, sm4, 16); SSTG(S7, sm3, 8); SSTG(S7, sm2, 4); SSTG(S7, sm1, 2); SSTG(S7, sm0, 1);
        float SC = AC, SE = AE;
        PSTG(SC, 32); PSTG(SC, 16); PSTG(SC, 8); PSTG(SC, 4); PSTG(SC, 2); PSTG(SC, 1);
        PSTG(SE, 32); PSTG(SE, 16); PSTG(SE, 8); PSTG(SE, 4); PSTG(SE, 2); PSTG(SE, 1);
#undef SSTG
#undef PSTG
        const int pWv = Wv0 ^ Wv1;
        if (L == 0) {
            red[Wv][0]  = pWv ? -S7 : S7;
            red[Wv][1]  = SC;
            red[Wv][2]  = SE;
            red[Wv][3]  = P;
            red[Wv][4]  = Wv1 ? -P : P;
            red[Wv][5]  = pWv ? -P : P;
            red[Wv][6]  = pWv ? -C20 : C20;
            red[Wv][7]  = pWv ? -C30 : C30;
            red[Wv][8]  = pWv ? -C38 : C38;
            red[Wv][9]  = pWv ? -C3C : C3C;
            red[Wv][10] = pWv ? -C3E : C3E;
            red[Wv][11] = pWv ? -F   : F;
        }
        __syncthreads();   // [barrier 3]
        if (t < NQ) out[b * NQ + t] = red[0][t] + red[1][t] + red[2][t] + red[3][t];
        if (ITERS > 1) __syncthreads();   // red reuse safety across iters
    }
}

extern "C" void kernel_launch(void* const* d_in, const int* in_sizes, int n_in,
                              void* d_out, int out_size, void* d_ws, size_t ws_size,
                              hipStream_t stream) {
    int xi = 0, wi = 1;
    if (n_in >= 2 && in_sizes[1] > in_sizes[0]) { xi = 1; wi = 0; }
    const float* x = (const float*)d_in[xi];
    const float* w = (const float*)d_in[wi];
    float* out = (float*)d_out;
    const int B = in_sizes[xi] / NQ;   // 1024
    // scored kernel
    qsim_kernel<1><<<B, NT, 0, stream>>>(x, w, out);
    // diagnostic: 4x-iterated clone writing to scratch, so the qsim dispatch
    // exceeds the 40us ws-poison fills and surfaces in the rocprof top-5
    // with counters ~4x the real kernel. Removed next round.
    qsim_kernel<4><<<B, NT, 0, stream>>>(x, w, (float*)d_ws);
}

// Round 10
// 69.297 us; speedup vs baseline: 1.7478x; 1.7478x over previous
//
#include <hip/hip_runtime.h>

#define NQ 12
#define NT 256   // 4 waves per block; one batch element per block; 16 amps/thread

typedef float v2 __attribute__((ext_vector_type(2)));

// ---------- GF(2)-linear index machinery (HW-verified R4..R9) ----------
__host__ __device__ constexpr int par12(int v) {
    v ^= v >> 8; v ^= v >> 4; v ^= v >> 2; v ^= v >> 1; return v & 1;
}
// LDS slot: SL'(i) = i ^ ((i>>4)&15). Linear; preserves bits 10-11 (wave id);
// all four era patterns are bank-pair-injective per 16-lane phase (R9 pm).
__device__ __forceinline__ v2 sel2(v2 a, v2 b, int c) { return c ? b : a; }

// ---- packed-friendly complex math: pure vector ops, no .x/.y writes ----
static __device__ const v2 SGN = {-1.f, 1.f};
__device__ __forceinline__ v2 cmadd(v2 c, v2 a, v2 acc) {
    v2 cb0 = __builtin_shufflevector(c, c, 0, 0);   // (c.re, c.re)
    v2 cb1 = __builtin_shufflevector(c, c, 1, 1);   // (c.im, c.im)
    v2 as  = __builtin_shufflevector(a, a, 1, 0);   // (a.im, a.re)
    acc = cb0 * a + acc;                            // pk_fma
    acc = cb1 * (as * SGN) + acc;                   // pk_fma (neg folds)
    return acc;
}
__device__ __forceinline__ v2 cmul(v2 c, v2 a) {
    v2 cb0 = __builtin_shufflevector(c, c, 0, 0);
    v2 cb1 = __builtin_shufflevector(c, c, 1, 1);
    v2 as  = __builtin_shufflevector(a, a, 1, 0);
    return cb0 * a + cb1 * (as * SGN);
}
__device__ __forceinline__ void gate2(v2& A0, v2& A1, v2 u00, v2 u01, v2 u10, v2 u11) {
    v2 n0 = cmadd(u01, A1, cmul(u00, A0));
    v2 n1 = cmadd(u11, A1, cmul(u10, A0));
    A0 = n0; A1 = n1;
}

__global__ __launch_bounds__(NT, 4) void qsim_kernel(
    const float* __restrict__ x,   // (B, 12) fp32
    const float* __restrict__ w,   // (2, 12, 3) fp32
    float* __restrict__ out)       // (B, 12) fp32
{
    __shared__ v2 sc[4096];                       // 32 KB state scratch
    __shared__ __align__(16) float fm[2][NQ][8];  // fused U = Rot*RY
    __shared__ float red[4][NQ];

    const int t  = threadIdx.x;
    const int L  = t & 63;
    const int Wv = t >> 6;        // wave id 0..3
    const int b  = blockIdx.x;

    // ---- fused gate matrices U = Rot(phi,theta,omega) * RY(x_q) ----
    if (t < 2 * NQ) {
        int l = t / NQ, q = t % NQ;
        float hy = 0.5f * x[b * NQ + q];
        float cy = cosf(hy), sy = sinf(hy);
        const float* wp = w + (l * NQ + q) * 3;
        float phi = wp[0], the = wp[1], om = wp[2];
        float c = cosf(0.5f * the), s = sinf(0.5f * the);
        float al = 0.5f * (phi + om), be = 0.5f * (phi - om);
        float ca = cosf(al), sa = sinf(al), cb = cosf(be), sb = sinf(be);
        float r00r =  ca * c, r00i = -sa * c;
        float r01r = -cb * s, r01i = -sb * s;
        float r10r =  cb * s, r10i = -sb * s;
        float r11r =  ca * c, r11i =  sa * c;
        float* m = fm[l][q];
        m[0] =  r00r * cy + r01r * sy;  m[1] =  r00i * cy + r01i * sy;  // U00
        m[2] = -r00r * sy + r01r * cy;  m[3] = -r00i * sy + r01i * cy;  // U01
        m[4] =  r10r * cy + r11r * sy;  m[5] =  r10i * cy + r11i * sy;  // U10
        m[6] = -r10r * sy + r11r * cy;  m[7] = -r10i * sy + r11i * cy;  // U11
    }

    // ---- era slot bases under SL'(i) = i ^ ((i>>4)&15) ----
    const int g0    = (Wv << 10) | (L << 4);
    const int rbase = g0 ^ (L & 15);                       // SL'(g0); T1 write: ^ r
    const int q1i   = (Wv << 10) | ((L >> 4) << 8) | (L & 15);  // SL'(q1i)=q1i
    // T1 read / T2 write: slot = q1i ^ (r<<4) ^ r
    const int q2t   = (Wv << 6) | L;
    const int q2s   = q2t ^ (L >> 4) ^ ((Wv & 3) << 2);    // SL'(q2t); T2 read: ^ (r<<8)
    const int L0 = L & 1, Wv0 = Wv & 1, Wv1 = Wv >> 1;
    // epilogue sign-flip masks per lane bit
    unsigned sm0 = (L & 1)  ? 0x80000000u : 0u;
    unsigned sm1 = (L & 2)  ? 0x80000000u : 0u;
    unsigned sm2 = (L & 4)  ? 0x80000000u : 0u;
    unsigned sm3 = (L & 8)  ? 0x80000000u : 0u;
    unsigned sm4 = (L & 16) ? 0x80000000u : 0u;
    unsigned sm5 = (L & 32) ? 0x80000000u : 0u;

    __syncthreads();   // fm ready  [barrier 1]

    // ==== post-ring1 state built DIRECTLY in registers (R9-verified) ====
    // amp(i) = prod_q v_q[x_{11-q}], x = ringInv(i), i = (Wv<<10)|(L<<4)|r.
    v2 A[16];
    {
        v2 C = sel2(*(const v2*)&fm[0][7][0], *(const v2*)&fm[0][7][4], (L ^ (L >> 1)) & 1);
        C = cmul(sel2(*(const v2*)&fm[0][6][0], *(const v2*)&fm[0][6][4], ((L >> 1) ^ (L >> 2)) & 1), C);
        C = cmul(sel2(*(const v2*)&fm[0][5][0], *(const v2*)&fm[0][5][4], ((L >> 2) ^ (L >> 3)) & 1), C);
        C = cmul(sel2(*(const v2*)&fm[0][4][0], *(const v2*)&fm[0][4][4], ((L >> 3) ^ (L >> 4)) & 1), C);
        C = cmul(sel2(*(const v2*)&fm[0][3][0], *(const v2*)&fm[0][3][4], ((L >> 4) ^ (L >> 5)) & 1), C);
        C = cmul(sel2(*(const v2*)&fm[0][2][0], *(const v2*)&fm[0][2][4], ((L >> 5) ^ Wv0) & 1), C);
        v2 v1a = sel2(*(const v2*)&fm[0][1][0], *(const v2*)&fm[0][1][4], Wv0 ^ Wv1);
        v2 v1b = sel2(*(const v2*)&fm[0][1][0], *(const v2*)&fm[0][1][4], Wv0 ^ Wv1 ^ 1);
        v2 v0a = sel2(*(const v2*)&fm[0][0][0], *(const v2*)&fm[0][0][4], Wv1);
        v2 v0b = sel2(*(const v2*)&fm[0][0][0], *(const v2*)&fm[0][0][4], Wv1 ^ 1);
        v2 A2[2];
        A2[0] = cmul(C, cmul(v1a, v0a));
        A2[1] = cmul(C, cmul(v1b, v0b));
        v2 e0 = *(const v2*)&fm[0][11][0], e1 = *(const v2*)&fm[0][11][4];
        v2 A4[4];
        A4[0] = cmul(e0, A2[0]); A4[1] = cmul(e1, A2[1]);   // r1=0
        A4[2] = cmul(e1, A2[0]); A4[3] = cmul(e0, A2[1]);   // r1=1
        v2 f0 = *(const v2*)&fm[0][10][0], f1 = *(const v2*)&fm[0][10][4];
        v2 A8[8];
#pragma unroll
        for (int rr = 0; rr < 8; ++rr) {
            int r1 = (rr >> 1) & 1, r2 = (rr >> 2) & 1;
            A8[rr] = cmul((r1 ^ r2) ? f1 : f0, A4[rr & 3]);
        }
        v2 n0 = *(const v2*)&fm[0][9][0], n1 = *(const v2*)&fm[0][9][4];
        v2 m8a = sel2(*(const v2*)&fm[0][8][0], *(const v2*)&fm[0][8][4], L0);
        v2 m8b = sel2(*(const v2*)&fm[0][8][0], *(const v2*)&fm[0][8][4], L0 ^ 1);
        v2 H[4];
        H[0] = cmul(n0, m8a);  // r2=0,r3=0
        H[1] = cmul(n1, m8a);  // r2=1,r3=0
        H[2] = cmul(n1, m8b);  // r2=0,r3=1
        H[3] = cmul(n0, m8b);  // r2=1,r3=1
#pragma unroll
        for (int r = 0; r < 16; ++r)
            A[r] = cmul(H[((r >> 2) & 1) + 2 * (r >> 3)], A8[r & 7]);
    }

    // ==== gates wires 11..8 (Q0 reg bit j <-> wire 11-j) ====
#pragma unroll
    for (int j = 0; j < 4; ++j) {
        const int q = 11 - j;
        float4 lo = *(const float4*)&fm[1][q][0], hi = *(const float4*)&fm[1][q][4];
        v2 u00 = {lo.x, lo.y}, u01 = {lo.z, lo.w}, u10 = {hi.x, hi.y}, u11 = {hi.z, hi.w};
#pragma unroll
        for (int r0 = 0; r0 < 16; ++r0) {
            if (r0 & (1 << j)) continue;
            gate2(A[r0], A[r0 | (1 << j)], u00, u01, u10, u11);
        }
    }

    // ==== T1: Q0 -> Q1 (wave-private slots under SL': no barrier) ====
#pragma unroll
    for (int r = 0; r < 16; ++r) sc[rbase ^ r] = A[r];
#pragma unroll
    for (int r = 0; r < 16; ++r) A[r] = sc[q1i ^ ((r << 4) ^ r)];

    // ==== gates wires 7..4 (Q1 reg bit j <-> wire 7-j) ====
#pragma unroll
    for (int j = 0; j < 4; ++j) {
        const int q = 7 - j;
        float4 lo = *(const float4*)&fm[1][q][0], hi = *(const float4*)&fm[1][q][4];
        v2 u00 = {lo.x, lo.y}, u01 = {lo.z, lo.w}, u10 = {hi.x, hi.y}, u11 = {hi.z, hi.w};
#pragma unroll
        for (int r0 = 0; r0 < 16; ++r0) {
            if (r0 & (1 << j)) continue;
            gate2(A[r0], A[r0 | (1 << j)], u00, u01, u10, u11);
        }
    }

    // ==== T2: Q1 -> Q2 (cross-wave) ====
#pragma unroll
    for (int r = 0; r < 16; ++r) sc[q1i ^ ((r << 4) ^ r)] = A[r];
    __syncthreads();   // [barrier 2]
#pragma unroll
    for (int r = 0; r < 16; ++r) A[r] = sc[q2s ^ (r << 8)];

    // ==== gates wires 3..0 (Q2 reg bit j <-> wire 3-j) ====
#pragma unroll
    for (int j = 0; j < 4; ++j) {
        const int q = 3 - j;
        float4 lo = *(const float4*)&fm[1][q][0], hi = *(const float4*)&fm[1][q][4];
        v2 u00 = {lo.x, lo.y}, u01 = {lo.z, lo.w}, u10 = {hi.x, hi.y}, u11 = {hi.z, hi.w};
#pragma unroll
        for (int r0 = 0; r0 < 16; ++r0) {
            if (r0 & (1 << j)) continue;
            gate2(A[r0], A[r0 | (1 << j)], u00, u01, u10, u11);
        }
    }

    // ==== epilogue: ring2 folded into signs (R8/R9-verified masks) ====
    float A7 = 0.f, AC = 0.f, AE = 0.f, AFv = 0.f;
#pragma unroll
    for (int r = 0; r < 16; ++r) {
        float p = A[r].x * A[r].x + A[r].y * A[r].y;
        A7  += par12(r & 0x7) ? -p : p;
        AC  += par12(r & 0xC) ? -p : p;
        AE  += par12(r & 0xE) ? -p : p;
        AFv += par12(r & 0xF) ? -p : p;
    }
#define SSTG(X, SM, OFF) { float y_ = __uint_as_float(__float_as_uint(X) ^ (SM)); X = y_ + __shfl_xor(y_, OFF, 64); }
#define PSTG(X, OFF)     { X += __shfl_xor(X, OFF, 64); }
    float F = AFv, P = AFv;
    SSTG(F, sm5, 32); PSTG(P, 32); float C20 = F;
    SSTG(F, sm4, 16); PSTG(P, 16); PSTG(C20, 16); float C30 = F;
    SSTG(F, sm3, 8);  PSTG(P, 8);  PSTG(C20, 8);  PSTG(C30, 8);  float C38 = F;
    SSTG(F, sm2, 4);  PSTG(P, 4);  PSTG(C20, 4);  PSTG(C30, 4);  PSTG(C38, 4); float C3C = F;
    SSTG(F, sm1, 2);  PSTG(P, 2);  PSTG(C20, 2);  PSTG(C30, 2);  PSTG(C38, 2); PSTG(C3C, 2); float C3E = F;
    SSTG(F, sm0, 1);  PSTG(P, 1);  PSTG(C20, 1);  PSTG(C30, 1);  PSTG(C38, 1); PSTG(C3C, 1); PSTG(C3E, 1);
    float S7 = A7;
    SSTG(S7, sm5, 32); SSTG(S7, sm4, 16); SSTG(S7, sm3, 8); SSTG(S7, sm2, 4); SSTG(S7, sm1, 2); SSTG(S7, sm0, 1);
    float SC = AC, SE = AE;
    PSTG(SC, 32); PSTG(SC, 16); PSTG(SC, 8); PSTG(SC, 4); PSTG(SC, 2); PSTG(SC, 1);
    PSTG(SE, 32); PSTG(SE, 16); PSTG(SE, 8); PSTG(SE, 4); PSTG(SE, 2); PSTG(SE, 1);
#undef SSTG
#undef PSTG
    const int pWv = Wv0 ^ Wv1;
    if (L == 0) {
        red[Wv][0]  = pWv ? -S7 : S7;
        red[Wv][1]  = SC;
        red[Wv][2]  = SE;
        red[Wv][3]  = P;
        red[Wv][4]  = Wv1 ? -P : P;
        red[Wv][5]  = pWv ? -P : P;
        red[Wv][6]  = pWv ? -C20 : C20;
        red[Wv][7]  = pWv ? -C30 : C30;
        red[Wv][8]  = pWv ? -C38 : C38;
        red[Wv][9]  = pWv ? -C3C : C3C;
        red[Wv][10] = pWv ? -C3E : C3E;
        red[Wv][11] = pWv ? -F   : F;
    }
    __syncthreads();   // [barrier 3]
    if (t < NQ) out[b * NQ + t] = red[0][t] + red[1][t] + red[2][t] + red[3][t];
}

extern "C" void kernel_launch(void* const* d_in, const int* in_sizes, int n_in,
                              void* d_out, int out_size, void* d_ws, size_t ws_size,
                              hipStream_t stream) {
    int xi = 0, wi = 1;
    if (n_in >= 2 && in_sizes[1] > in_sizes[0]) { xi = 1; wi = 0; }
    const float* x = (const float*)d_in[xi];
    const float* w = (const float*)d_in[wi];
    float* out = (float*)d_out;
    const int B = in_sizes[xi] / NQ;   // 1024
    qsim_kernel<<<B, NT, 0, stream>>>(x, w, out);
}